// Round 5
// baseline (51770.221 us; speedup 1.0000x reference)
//
#include <hip/hip_runtime.h>
#include <cstdint>
#include <cstddef>

__device__ __forceinline__ float sigf(float x) { return 1.f / (1.f + expf(-x)); }

static constexpr int TT = 8192;   // frames
static constexpr int MM = 64;     // actions
static constexpr int CC = 32;     // classes
static constexpr int DD = 512;    // model dim

// ---------------------------------------------------------------- ws zeroing
__global__ void zero_k(float* __restrict__ p, long n) {
  long i = (long)blockIdx.x * 256 + threadIdx.x;
  long stride = (long)gridDim.x * 256;
  for (; i < n; i += stride) p[i] = 0.f;
}

// ---------------------------------------------------------------- elementwise
__global__ void copy_k(const float* __restrict__ a, float* __restrict__ o, int n) {
  int i = blockIdx.x * 256 + threadIdx.x;
  if (i < n) o[i] = a[i];
}
__global__ void addff_k(const float* __restrict__ a, const float* __restrict__ b, float* __restrict__ o, int n) {
  int i = blockIdx.x * 256 + threadIdx.x;
  if (i < n) o[i] = a[i] + b[i];
}
__global__ void acomb_k(const float* __restrict__ hf, const float* __restrict__ hb, float* __restrict__ o, int n) {
  int i = blockIdx.x * 256 + threadIdx.x;
  if (i >= n) return;
  int s = i >> 9, j = i & 511;
  float v = (j < 256) ? hf[(size_t)s * 256 + j] : hb[(size_t)s * 256 + (j - 256)];
  o[i] = fmaxf(v, 0.f);
}
__global__ void gatherpos_k(const float* __restrict__ fpos, const int* __restrict__ centers,
                            float* __restrict__ segpos, int n) {
  int i = blockIdx.x * 256 + threadIdx.x;
  if (i >= n) return;
  int s = i >> 9, dd = i & 511;
  int ct = centers[s];
  ct = ct < 0 ? 0 : (ct > TT - 1 ? TT - 1 : ct);
  segpos[i] = fpos[(size_t)ct * 512 + dd];
}

// ---------------------------------------------------------------- text norms
__global__ void tnorm_k(const float* __restrict__ text, float* __restrict__ tnorm) {
  int c = blockIdx.x * 256 + threadIdx.x;
  if (c >= 32) return;
  float s = 0.f;
  for (int dd = 0; dd < 512; dd++) { float v = text[(size_t)c * 512 + dd]; s += v * v; }
  tnorm[c] = sqrtf(s);
}

// ---------------------------------------------------- naive GEMM
__global__ void ngemm_k(const float* __restrict__ A, const float* __restrict__ B,
                        const float* __restrict__ bias, float* __restrict__ C,
                        int M, int N, int K) {
  int idx = blockIdx.x * 256 + threadIdx.x;
  if (idx >= M * N) return;
  int m = idx / N, n = idx - m * N;
  float a = bias ? bias[n] : 0.f;
  const float* Ar = A + (size_t)m * K;
  for (int k = 0; k < K; k++) a += Ar[k] * B[(size_t)k * N + n];
  C[idx] = a;
}

// ---------------------------------------------------- naive attention pieces
__global__ void nlogit_k(const float* __restrict__ Q, const float* __restrict__ Kk,
                         float* __restrict__ L, int NY, int NX) {
  int idx = blockIdx.x * 256 + threadIdx.x;
  if (idx >= NY * NX) return;
  int y = idx / NX, x = idx - y * NX;
  const float* qr = Q + (size_t)y * 512;
  const float* kr = Kk + (size_t)x * 512;
  float d = 0.f;
  for (int k = 0; k < 512; k++) d += qr[k] * kr[k];
  L[idx] = d * 0.044194173824159216f;  // 1/sqrt(512)
}
__global__ void nsoft_k(float* __restrict__ L, int NY, int NX) {  // 1 thread / row
  int y = blockIdx.x * 256 + threadIdx.x;
  if (y >= NY) return;
  float* row = L + (size_t)y * NX;
  float m = row[0];
  for (int x = 1; x < NX; x++) m = fmaxf(m, row[x]);
  float s = 0.f;
  for (int x = 0; x < NX; x++) { float p = expf(row[x] - m); row[x] = p; s += p; }
  const float inv = 1.f / s;
  for (int x = 0; x < NX; x++) row[x] *= inv;
}
__global__ void nav_k(const float* __restrict__ P, const float* __restrict__ V,
                      float* __restrict__ O, int NY, int NX) {
  int idx = blockIdx.x * 256 + threadIdx.x;
  if (idx >= NY * 512) return;
  int y = idx >> 9, dd = idx & 511;
  const float* pr = P + (size_t)y * NX;
  float o = 0.f;
  for (int x = 0; x < NX; x++) o += pr[x] * V[(size_t)x * 512 + dd];
  O[idx] = o;
}

// ------------------------------------------------------ naive argmax (pred)
__global__ void nargmax_k(const float* __restrict__ V, const float* __restrict__ text,
                          const float* __restrict__ tnorm, int* __restrict__ pred) {
  int r = blockIdx.x * 256 + threadIdx.x;
  if (r >= TT) return;
  const float* vr = V + (size_t)r * 512;
  float best = -1e30f; int bc = 0;
  for (int c = 0; c < 32; c++) {
    float dot = 0.f;
    for (int dd = 0; dd < 512; dd++) dot += vr[dd] * text[(size_t)c * 512 + dd];
    dot /= tnorm[c];
    if (dot > best) { best = dot; bc = c; }
  }
  pred[r] = bc;
}

// ------------------------------------- sequential segmentation (single thread)
__global__ void nseg_k(const int* __restrict__ pred, int* __restrict__ segid,
                       int* __restrict__ starts, int* __restrict__ centers,
                       int* __restrict__ cnts) {
  if (blockIdx.x != 0 || threadIdx.x != 0) return;
  int sid = 0;
  starts[0] = 0;
  for (int t = 0; t < TT; t++) {
    if (t > 0 && pred[t] != pred[t - 1]) { sid++; starts[sid] = t; }
    segid[t] = sid;
  }
  const int Sd = sid + 1;
  for (int s = 0; s < TT; s++) {
    if (s < Sd) {
      int e = (s == Sd - 1) ? (TT - 1) : (starts[s + 1] - 1);
      centers[s] = (starts[s] + e) >> 1;
      cnts[s] = e - starts[s] + 1;
    } else { starts[s] = 0; cnts[s] = 1; centers[s] = 0; }
  }
}

// ---------------------------------------------------------- segment mean pool
__global__ void segmean_k(const float* __restrict__ ff, const int* __restrict__ starts,
                          const int* __restrict__ cnts, float* __restrict__ segmean, int S) {
  int idx = blockIdx.x * 256 + threadIdx.x;
  if (idx >= S * 512) return;
  int s = idx >> 9, dd = idx & 511;
  int st = starts[s], n = cnts[s];
  st = st < 0 ? 0 : (st > TT - 1 ? TT - 1 : st);
  n = n < 1 ? 1 : n;
  if (st + n > TT) n = TT - st;
  float a = 0.f;
  for (int t = st; t < st + n; t++) a += ff[(size_t)t * 512 + dd];
  segmean[idx] = a / (float)n;
}

// ----------------------------------------------- GRU single step (one launch)
__global__ void grustep_k(const float* __restrict__ gi_row, const float* __restrict__ Whh,
                          const float* __restrict__ bhh, const float* __restrict__ h_in,
                          float* __restrict__ h_out, float* __restrict__ ho_row, int H) {
  extern __shared__ float ghs[];
  const int tid = threadIdx.x;
  const int G = 3 * H;
  for (int j = tid; j < G; j += 768) {
    float gh = bhh[j];
    for (int i = 0; i < H; i++) gh += h_in[i] * Whh[(size_t)i * G + j];
    ghs[j] = gh;
  }
  __syncthreads();
  for (int j = tid; j < H; j += 768) {
    float r = sigf(gi_row[j] + ghs[j]);
    float z = sigf(gi_row[H + j] + ghs[H + j]);
    float nn = tanhf(gi_row[2 * H + j] + r * ghs[2 * H + j]);
    float hn = (1.f - z) * nn + z * h_in[j];
    h_out[j] = hn;
    ho_row[j] = hn;
  }
}

// ---------------------------- naive ff2: Y(D,T) = relu([seg2[sid],ff] @ Wsf + b)^T
__global__ void nff2_k(const float* __restrict__ seg2, const float* __restrict__ ff,
                       const int* __restrict__ segid, const float* __restrict__ Wsf,
                       const float* __restrict__ bsf, float* __restrict__ Y, int S) {
  int idx = blockIdx.x * 256 + threadIdx.x;  // n*TT + t
  if (idx >= 512 * TT) return;
  int n = idx >> 13, t = idx & (TT - 1);
  int sid = segid[t];
  sid = sid < 0 ? 0 : (sid >= S ? S - 1 : sid);
  float a = bsf[n];
  const float* sr = seg2 + (size_t)sid * 512;
  const float* fr = ff + (size_t)t * 512;
  for (int k = 0; k < 512; k++) a += sr[k] * Wsf[(size_t)k * 512 + n];
  for (int k = 0; k < 512; k++) a += fr[k] * Wsf[(size_t)(512 + k) * 512 + n];
  Y[idx] = fmaxf(a, 0.f);
}

// ------------------------------------------------------------ naive TCN conv
// X,Y: (512,T).  NTAPS==1: W[o][i]; NTAPS==3: W[o][i][3], 'SAME', dilation d.
template<int NTAPS, int RELU, int RES>
__global__ void nconv_k(const float* __restrict__ X, const float* __restrict__ W,
                        const float* __restrict__ bias, const float* __restrict__ Res,
                        float* __restrict__ Y, int dil) {
  int idx = blockIdx.x * 256 + threadIdx.x;  // c*TT + t
  if (idx >= 512 * TT) return;
  int c = idx >> 13, t = idx & (TT - 1);
  float a = bias[c];
  if (NTAPS == 1) {
    const float* wr = W + (size_t)c * 512;
    for (int i = 0; i < 512; i++) a += X[(size_t)i * TT + t] * wr[i];
  } else {
    const float* wr = W + (size_t)c * 512 * 3;
    for (int i = 0; i < 512; i++) {
      const float* xr = X + (size_t)i * TT;
      float x0 = (t >= dil) ? xr[t - dil] : 0.f;
      float x1 = xr[t];
      float x2 = (t + dil < TT) ? xr[t + dil] : 0.f;
      a += wr[i * 3 + 0] * x0 + wr[i * 3 + 1] * x1 + wr[i * 3 + 2] * x2;
    }
  }
  if (RES) a += Res[idx];
  if (RELU) a = fmaxf(a, 0.f);
  Y[idx] = a;
}

// ----------------------- naive transpose (512,T)->(T,512): out + f32 copy
__global__ void ntemit_k(const float* __restrict__ Xin, float* __restrict__ outp,
                         float* __restrict__ Aout) {
  int idx = blockIdx.x * 256 + threadIdx.x;  // t*512 + d
  if (idx >= TT * 512) return;
  int t = idx >> 9, dd = idx & 511;
  float v = Xin[(size_t)dd * TT + t];
  outp[idx] = v;
  Aout[idx] = v;
}

// ---------------------------------------------------------------- cosine sim
__global__ void nsim_k(const float* __restrict__ V, const float* __restrict__ text,
                       const float* __restrict__ tnorm, float* __restrict__ out, int R) {
  int idx = blockIdx.x * 256 + threadIdx.x;  // r*32 + c
  if (idx >= R * 32) return;
  int r = idx >> 5, c = idx & 31;
  const float* vr = V + (size_t)r * 512;
  float ss = 0.f, dot = 0.f;
  for (int dd = 0; dd < 512; dd++) {
    float v = vr[dd];
    ss += v * v;
    dot += v * text[(size_t)c * 512 + dd];
  }
  out[idx] = dot / (sqrtf(ss) * tnorm[c]);
}

// ======================================================================= host
extern "C" void kernel_launch(void* const* d_in, const int* in_sizes, int n_in,
                              void* d_out, int out_size, void* d_ws, size_t ws_size,
                              hipStream_t stream) {
  const float* in_ff   = (const float*)d_in[0];
  const float* in_act  = (const float*)d_in[1];
  const float* in_fpos = (const float*)d_in[2];
  const float* in_apos = (const float*)d_in[3];
  const float* in_text = (const float*)d_in[4];
  const float* Wf2c = (const float*)d_in[5];  const float* bf2c = (const float*)d_in[6];
  const float* Wa2c = (const float*)d_in[7];  const float* ba2c = (const float*)d_in[8];
  const float* Ws2c = (const float*)d_in[9];  const float* bs2c = (const float*)d_in[10];
  const float* Wih_f = (const float*)d_in[11]; const float* Whh_f = (const float*)d_in[12];
  const float* bih_f = (const float*)d_in[13]; const float* bhh_f = (const float*)d_in[14];
  const float* Wih_b = (const float*)d_in[15]; const float* Whh_b = (const float*)d_in[16];
  const float* bih_b = (const float*)d_in[17]; const float* bhh_b = (const float*)d_in[18];
  const float* Wcomb = (const float*)d_in[19]; const float* bcomb = (const float*)d_in[20];
  const float* f2a_Wq = (const float*)d_in[21]; const float* f2a_Wk = (const float*)d_in[22];
  const float* f2a_Wv = (const float*)d_in[23]; const float* f2a_Wo = (const float*)d_in[24];
  const float* f2a_bo = (const float*)d_in[25];
  const float* ag_Wih = (const float*)d_in[26]; const float* ag_Whh = (const float*)d_in[27];
  const float* ag_bih = (const float*)d_in[28]; const float* ag_bhh = (const float*)d_in[29];
  const float* a2f_Wq = (const float*)d_in[30]; const float* a2f_Wk = (const float*)d_in[31];
  const float* a2f_Wv = (const float*)d_in[32]; const float* a2f_Wo = (const float*)d_in[33];
  const float* a2f_bo = (const float*)d_in[34];
  const float* Wsf = (const float*)d_in[35]; const float* bsf = (const float*)d_in[36];
  const float* tcn_inW = (const float*)d_in[37]; const float* tcn_inb = (const float*)d_in[38];
  const float* tcn_dW = (const float*)d_in[39]; const float* tcn_db = (const float*)d_in[40];
  const float* tcn_pW = (const float*)d_in[41]; const float* tcn_pb = (const float*)d_in[42];
  const float* tcn_outW = (const float*)d_in[43]; const float* tcn_outb = (const float*)d_in[44];

  int S = (out_size - (TT * DD + MM * DD + TT * CC + MM * CC)) / CC;
  if (S < 1) S = 1;
  if (S > TT) S = TT;

  // ---------------- workspace layout
  char* ws = (char*)d_ws;
  size_t off = 0;
  auto alloc = [&](size_t b) -> char* { char* p = ws + off; off += (b + 255) & ~(size_t)255; return p; };
  const size_t BTD = (size_t)TT * DD * 4;
  float* bufA = (float*)alloc(BTD);
  float* bufB = (float*)alloc(BTD);
  int* pred    = (int*)alloc((size_t)TT * 4);
  int* segid   = (int*)alloc((size_t)TT * 4);
  int* starts  = (int*)alloc((size_t)TT * 4);
  int* centers = (int*)alloc((size_t)TT * 4);
  int* cnts    = (int*)alloc((size_t)TT * 4);
  float* tnorm = (float*)alloc(32 * 4);
  float* hP0 = (float*)alloc(512 * 4);
  float* hP1 = (float*)alloc(512 * 4);
  float* hQ0 = (float*)alloc(512 * 4);
  float* hQ1 = (float*)alloc(512 * 4);
  float* hR0 = (float*)alloc(512 * 4);
  float* hR1 = (float*)alloc(512 * 4);
  float* segmean = (float*)alloc((size_t)S * 512 * 4);
  float* gif  = (float*)alloc((size_t)S * 768 * 4);
  float* gib  = (float*)alloc((size_t)S * 768 * 4);
  float* hfb  = (float*)alloc((size_t)S * 256 * 4);
  float* hbb  = (float*)alloc((size_t)S * 256 * 4);
  float* acmb = (float*)alloc((size_t)S * 512 * 4);
  float* segc = (float*)alloc((size_t)S * 512 * 4);
  float* segpos = (float*)alloc((size_t)S * 512 * 4);
  float* kin  = (float*)alloc((size_t)S * 512 * 4);
  float* kf2a = (float*)alloc((size_t)S * 512 * 4);
  float* vf2a = (float*)alloc((size_t)S * 512 * 4);
  float* q2   = (float*)alloc((size_t)S * 512 * 4);
  float* att2 = (float*)alloc((size_t)S * 512 * 4);
  float* seg2 = (float*)alloc((size_t)S * 512 * 4);
  float* vseg = (float*)alloc((size_t)S * 512 * 4);
  float* pbuf = (float*)alloc((size_t)64 * S * 4);
  float* qin  = (float*)alloc((size_t)64 * 512 * 4);
  float* qf2a = (float*)alloc((size_t)64 * 512 * 4);
  float* att1 = (float*)alloc((size_t)64 * 512 * 4);
  float* af0  = (float*)alloc((size_t)64 * 512 * 4);
  float* aggi = (float*)alloc((size_t)64 * 1536 * 4);
  float* afg  = (float*)alloc((size_t)64 * 512 * 4);
  float* k2in = (float*)alloc((size_t)64 * 512 * 4);
  float* k2   = (float*)alloc((size_t)64 * 512 * 4);
  float* v2   = (float*)alloc((size_t)64 * 512 * 4);
  float* vaf  = (float*)alloc((size_t)64 * 512 * 4);
  (void)ws_size; (void)in_sizes; (void)n_in;

  float* outp = (float*)d_out;
  float* out_ff   = outp;
  float* out_af   = outp + (size_t)TT * DD;
  float* out_fsim = out_af + (size_t)MM * DD;
  float* out_asim = out_fsim + (size_t)TT * CC;
  float* out_ssim = out_asim + (size_t)MM * CC;

  auto GR = [](long n) { return (unsigned)((n + 255) / 256); };

  // zero every ws byte we will touch (also establishes GRU h0 = 0)
  zero_k<<<4096, 256, 0, stream>>>((float*)d_ws, (long)(off / 4));

  tnorm_k<<<1, 256, 0, stream>>>(in_text, tnorm);

  // segmentation
  ngemm_k<<<GR((long)TT * 512), 256, 0, stream>>>(in_ff, Wf2c, bf2c, bufA, TT, 512, 512);
  nargmax_k<<<GR(TT), 256, 0, stream>>>(bufA, in_text, tnorm, pred);
  nseg_k<<<1, 64, 0, stream>>>(pred, segid, starts, centers, cnts);
  segmean_k<<<GR((long)S * 512), 256, 0, stream>>>(in_ff, starts, cnts, segmean, S);

  // seg BiGRU: input gates + one launch per timestep
  ngemm_k<<<GR((long)S * 768), 256, 0, stream>>>(segmean, Wih_f, bih_f, gif, S, 768, 512);
  ngemm_k<<<GR((long)S * 768), 256, 0, stream>>>(segmean, Wih_b, bih_b, gib, S, 768, 512);
  for (int step = 0; step < S; step++) {
    const float* hi = (step & 1) ? hP1 : hP0;
    float* ho = (step & 1) ? hP0 : hP1;
    grustep_k<<<1, 768, 768 * 4, stream>>>(gif + (size_t)step * 768, Whh_f, bhh_f,
                                           hi, ho, hfb + (size_t)step * 256, 256);
  }
  for (int step = 0; step < S; step++) {
    const int s = S - 1 - step;
    const float* hi = (step & 1) ? hQ1 : hQ0;
    float* ho = (step & 1) ? hQ0 : hQ1;
    grustep_k<<<1, 768, 768 * 4, stream>>>(gib + (size_t)s * 768, Whh_b, bhh_b,
                                           hi, ho, hbb + (size_t)s * 256, 256);
  }
  acomb_k<<<GR((long)S * 512), 256, 0, stream>>>(hfb, hbb, acmb, S * 512);
  ngemm_k<<<GR((long)S * 512), 256, 0, stream>>>(acmb, Wcomb, bcomb, segc, S, 512, 512);
  gatherpos_k<<<GR((long)S * 512), 256, 0, stream>>>(in_fpos, centers, segpos, S * 512);

  // f2a attention (actions query segments)
  addff_k<<<GR(64 * 512), 256, 0, stream>>>(in_act, in_apos, qin, 64 * 512);
  addff_k<<<GR((long)S * 512), 256, 0, stream>>>(segc, segpos, kin, S * 512);
  ngemm_k<<<GR(64 * 512), 256, 0, stream>>>(qin, f2a_Wq, nullptr, qf2a, 64, 512, 512);
  ngemm_k<<<GR((long)S * 512), 256, 0, stream>>>(kin, f2a_Wk, nullptr, kf2a, S, 512, 512);
  ngemm_k<<<GR((long)S * 512), 256, 0, stream>>>(segc, f2a_Wv, nullptr, vf2a, S, 512, 512);
  nlogit_k<<<GR((long)64 * S), 256, 0, stream>>>(qf2a, kf2a, pbuf, 64, S);
  nsoft_k<<<1, 256, 0, stream>>>(pbuf, 64, S);
  nav_k<<<GR(64 * 512), 256, 0, stream>>>(pbuf, vf2a, att1, 64, S);
  ngemm_k<<<GR(64 * 512), 256, 0, stream>>>(att1, f2a_Wo, f2a_bo, af0, 64, 512, 512);

  // action GRU (H=512), one launch per step
  ngemm_k<<<GR(64 * 1536), 256, 0, stream>>>(af0, ag_Wih, ag_bih, aggi, 64, 1536, 512);
  for (int step = 0; step < MM; step++) {
    const float* hi = (step & 1) ? hR1 : hR0;
    float* ho = (step & 1) ? hR0 : hR1;
    grustep_k<<<1, 768, 1536 * 4, stream>>>(aggi + (size_t)step * 1536, ag_Whh, ag_bhh,
                                            hi, ho, afg + (size_t)step * 512, 512);
  }
  copy_k<<<GR(64 * 512), 256, 0, stream>>>(afg, out_af, 64 * 512);

  // a2f attention (segments query actions)
  addff_k<<<GR(64 * 512), 256, 0, stream>>>(afg, in_apos, k2in, 64 * 512);
  ngemm_k<<<GR((long)S * 512), 256, 0, stream>>>(kin, a2f_Wq, nullptr, q2, S, 512, 512);
  ngemm_k<<<GR(64 * 512), 256, 0, stream>>>(k2in, a2f_Wk, nullptr, k2, 64, 512, 512);
  ngemm_k<<<GR(64 * 512), 256, 0, stream>>>(afg, a2f_Wv, nullptr, v2, 64, 512, 512);
  nlogit_k<<<GR((long)S * 64), 256, 0, stream>>>(q2, k2, pbuf, S, 64);
  nsoft_k<<<GR(S), 256, 0, stream>>>(pbuf, S, 64);
  nav_k<<<GR((long)S * 512), 256, 0, stream>>>(pbuf, v2, att2, S, 64);
  ngemm_k<<<GR((long)S * 512), 256, 0, stream>>>(att2, a2f_Wo, a2f_bo, seg2, S, 512, 512);

  // frame fusion + TCN (naive), ping-pong bufA <-> bufB as (D,T)
  nff2_k<<<GR((long)512 * TT), 256, 0, stream>>>(seg2, in_ff, segid, Wsf, bsf, bufA, S);
  nconv_k<1, 0, 0><<<GR((long)512 * TT), 256, 0, stream>>>(bufA, tcn_inW, tcn_inb, nullptr, bufB, 1);
  for (int l = 0; l < 6; l++) {
    nconv_k<3, 1, 0><<<GR((long)512 * TT), 256, 0, stream>>>(
        bufB, tcn_dW + (size_t)l * 512 * 512 * 3, tcn_db + (size_t)l * 512, nullptr, bufA, 1 << l);
    nconv_k<1, 0, 1><<<GR((long)512 * TT), 256, 0, stream>>>(
        bufA, tcn_pW + (size_t)l * 512 * 512, tcn_pb + (size_t)l * 512, bufB, bufB, 1);
  }
  nconv_k<1, 0, 0><<<GR((long)512 * TT), 256, 0, stream>>>(bufB, tcn_outW, tcn_outb, nullptr, bufA, 1);
  ntemit_k<<<GR((long)TT * 512), 256, 0, stream>>>(bufA, out_ff, bufB);

  // similarity heads
  ngemm_k<<<GR((long)TT * 512), 256, 0, stream>>>(bufB, Wf2c, bf2c, bufA, TT, 512, 512);
  nsim_k<<<GR((long)TT * 32), 256, 0, stream>>>(bufA, in_text, tnorm, out_fsim, TT);
  ngemm_k<<<GR(64 * 512), 256, 0, stream>>>(afg, Wa2c, ba2c, vaf, 64, 512, 512);
  nsim_k<<<GR(64 * 32), 256, 0, stream>>>(vaf, in_text, tnorm, out_asim, 64);
  ngemm_k<<<GR((long)S * 512), 256, 0, stream>>>(seg2, Ws2c, bs2c, vseg, S, 512, 512);
  nsim_k<<<GR((long)S * 32), 256, 0, stream>>>(vseg, in_text, tnorm, out_ssim, S);
}

// Round 6
// 11785.700 us; speedup vs baseline: 4.3926x; 4.3926x over previous
//
#include <hip/hip_runtime.h>
#include <cstdint>
#include <cstddef>

__device__ __forceinline__ float sigf(float x) { return 1.f / (1.f + expf(-x)); }

static constexpr int TT = 8192;   // frames
static constexpr int MM = 64;     // actions
static constexpr int CC = 32;     // classes
static constexpr int DD = 512;    // model dim

// ---------------------------------------------------------------- ws zeroing
__global__ void zero_k(float* __restrict__ p, long n) {
  long i = (long)blockIdx.x * 256 + threadIdx.x;
  long stride = (long)gridDim.x * 256;
  for (; i < n; i += stride) p[i] = 0.f;
}

// ---------------------------------------------------------------- elementwise
__global__ void copy_k(const float* __restrict__ a, float* __restrict__ o, int n) {
  int i = blockIdx.x * 256 + threadIdx.x;
  if (i < n) o[i] = a[i];
}
__global__ void addff_k(const float* __restrict__ a, const float* __restrict__ b, float* __restrict__ o, int n) {
  int i = blockIdx.x * 256 + threadIdx.x;
  if (i < n) o[i] = a[i] + b[i];
}
__global__ void acomb_k(const float* __restrict__ hf, const float* __restrict__ hb, float* __restrict__ o, int n) {
  int i = blockIdx.x * 256 + threadIdx.x;
  if (i >= n) return;
  int s = i >> 9, j = i & 511;
  float v = (j < 256) ? hf[(size_t)s * 256 + j] : hb[(size_t)s * 256 + (j - 256)];
  o[i] = fmaxf(v, 0.f);
}
__global__ void gatherpos_k(const float* __restrict__ fpos, const int* __restrict__ centers,
                            float* __restrict__ segpos, int n) {
  int i = blockIdx.x * 256 + threadIdx.x;
  if (i >= n) return;
  int s = i >> 9, dd = i & 511;
  int ct = centers[s];
  ct = ct < 0 ? 0 : (ct > TT - 1 ? TT - 1 : ct);
  segpos[i] = fpos[(size_t)ct * 512 + dd];
}

// ---------------------------------------------------------------- text norms
__global__ void tnorm_k(const float* __restrict__ text, float* __restrict__ tnorm) {
  int c = blockIdx.x * 256 + threadIdx.x;
  if (c >= 32) return;
  float s = 0.f;
  for (int dd = 0; dd < 512; dd++) { float v = text[(size_t)c * 512 + dd]; s += v * v; }
  tnorm[c] = sqrtf(s);
}

// ---------------------------------------------------- naive GEMM (small ops)
__global__ void ngemm_k(const float* __restrict__ A, const float* __restrict__ B,
                        const float* __restrict__ bias, float* __restrict__ C,
                        int M, int N, int K) {
  int idx = blockIdx.x * 256 + threadIdx.x;
  if (idx >= M * N) return;
  int m = idx / N, n = idx - m * N;
  float a = bias ? bias[n] : 0.f;
  const float* Ar = A + (size_t)m * K;
  for (int k = 0; k < K; k++) a += Ar[k] * B[(size_t)k * N + n];
  C[idx] = a;
}

// ---------------------------------------------------- naive attention pieces
__global__ void nlogit_k(const float* __restrict__ Q, const float* __restrict__ Kk,
                         float* __restrict__ L, int NY, int NX) {
  int idx = blockIdx.x * 256 + threadIdx.x;
  if (idx >= NY * NX) return;
  int y = idx / NX, x = idx - y * NX;
  const float* qr = Q + (size_t)y * 512;
  const float* kr = Kk + (size_t)x * 512;
  float d = 0.f;
  for (int k = 0; k < 512; k++) d += qr[k] * kr[k];
  L[idx] = d * 0.044194173824159216f;  // 1/sqrt(512)
}
__global__ void nsoft_k(float* __restrict__ L, int NY, int NX) {  // 1 thread / row
  int y = blockIdx.x * 256 + threadIdx.x;
  if (y >= NY) return;
  float* row = L + (size_t)y * NX;
  float m = row[0];
  for (int x = 1; x < NX; x++) m = fmaxf(m, row[x]);
  float s = 0.f;
  for (int x = 0; x < NX; x++) { float p = expf(row[x] - m); row[x] = p; s += p; }
  const float inv = 1.f / s;
  for (int x = 0; x < NX; x++) row[x] *= inv;
}
__global__ void nav_k(const float* __restrict__ P, const float* __restrict__ V,
                      float* __restrict__ O, int NY, int NX) {
  int idx = blockIdx.x * 256 + threadIdx.x;
  if (idx >= NY * 512) return;
  int y = idx >> 9, dd = idx & 511;
  const float* pr = P + (size_t)y * NX;
  float o = 0.f;
  for (int x = 0; x < NX; x++) o += pr[x] * V[(size_t)x * 512 + dd];
  O[idx] = o;
}

// ------------------------------------------------------ naive argmax (pred)
__global__ void nargmax_k(const float* __restrict__ V, const float* __restrict__ text,
                          const float* __restrict__ tnorm, int* __restrict__ pred) {
  int r = blockIdx.x * 256 + threadIdx.x;
  if (r >= TT) return;
  const float* vr = V + (size_t)r * 512;
  float best = -1e30f; int bc = 0;
  for (int c = 0; c < 32; c++) {
    float dot = 0.f;
    for (int dd = 0; dd < 512; dd++) dot += vr[dd] * text[(size_t)c * 512 + dd];
    dot /= tnorm[c];
    if (dot > best) { best = dot; bc = c; }
  }
  pred[r] = bc;
}

// ------------------------------------- sequential segmentation (single thread)
__global__ void nseg_k(const int* __restrict__ pred, int* __restrict__ segid,
                       int* __restrict__ starts, int* __restrict__ centers,
                       int* __restrict__ cnts) {
  if (blockIdx.x != 0 || threadIdx.x != 0) return;
  int sid = 0;
  starts[0] = 0;
  for (int t = 0; t < TT; t++) {
    if (t > 0 && pred[t] != pred[t - 1]) { sid++; starts[sid] = t; }
    segid[t] = sid;
  }
  const int Sd = sid + 1;
  for (int s = 0; s < TT; s++) {
    if (s < Sd) {
      int e = (s == Sd - 1) ? (TT - 1) : (starts[s + 1] - 1);
      centers[s] = (starts[s] + e) >> 1;
      cnts[s] = e - starts[s] + 1;
    } else { starts[s] = 0; cnts[s] = 1; centers[s] = 0; }
  }
}

// ---------------------------------------------------------- segment mean pool
__global__ void segmean_k(const float* __restrict__ ff, const int* __restrict__ starts,
                          const int* __restrict__ cnts, float* __restrict__ segmean, int S) {
  int idx = blockIdx.x * 256 + threadIdx.x;
  if (idx >= S * 512) return;
  int s = idx >> 9, dd = idx & 511;
  int st = starts[s], n = cnts[s];
  st = st < 0 ? 0 : (st > TT - 1 ? TT - 1 : st);
  n = n < 1 ? 1 : n;
  if (st + n > TT) n = TT - st;
  float a = 0.f;
  for (int t = st; t < st + n; t++) a += ff[(size_t)t * 512 + dd];
  segmean[idx] = a / (float)n;
}

// ----------------------------------------- fused bidirectional seg GRU (H=256)
__launch_bounds__(768)
__global__ void gru_seg_k(const float* __restrict__ gi_f, const float* __restrict__ gi_b,
                          const float* __restrict__ Whh_f, const float* __restrict__ bhh_f,
                          const float* __restrict__ Whh_b, const float* __restrict__ bhh_b,
                          float* __restrict__ hf, float* __restrict__ hb, int S) {
  const bool bwd = (blockIdx.x == 1);
  const float* gi = bwd ? gi_b : gi_f;
  const float* Whh = bwd ? Whh_b : Whh_f;
  const float* bhh = bwd ? bhh_b : bhh_f;
  float* ho = bwd ? hb : hf;
  __shared__ float h[256];
  __shared__ float ghs[768];
  const int tid = threadIdx.x;
  if (tid < 256) h[tid] = 0.f;
  const float bj = bhh[tid];
  __syncthreads();
  for (int step = 0; step < S; step++) {
    const int s = bwd ? (S - 1 - step) : step;
    float gh = bj;
#pragma unroll 8
    for (int i = 0; i < 256; i++) gh += h[i] * Whh[(size_t)i * 768 + tid];
    ghs[tid] = gh;
    __syncthreads();
    if (tid < 256) {
      const float r = sigf(gi[(size_t)s * 768 + tid] + ghs[tid]);
      const float z = sigf(gi[(size_t)s * 768 + 256 + tid] + ghs[256 + tid]);
      const float nn = tanhf(gi[(size_t)s * 768 + 512 + tid] + r * ghs[512 + tid]);
      const float hn = (1.f - z) * nn + z * h[tid];
      h[tid] = hn;
      ho[(size_t)s * 256 + tid] = hn;
    }
    __syncthreads();
  }
}

// ----------------------------------------------- fused action GRU (H=512)
__launch_bounds__(768)
__global__ void gru_act_k(const float* __restrict__ gi, const float* __restrict__ Whh,
                          const float* __restrict__ bhh, float* __restrict__ hout, int steps) {
  __shared__ float h[512];
  __shared__ float ghs[1536];
  const int tid = threadIdx.x;
  if (tid < 512) h[tid] = 0.f;
  const float bj0 = bhh[tid];
  const float bj1 = bhh[tid + 768];
  __syncthreads();
  for (int step = 0; step < steps; step++) {
    float g0 = bj0, g1 = bj1;
#pragma unroll 8
    for (int i = 0; i < 512; i++) {
      const float hv = h[i];
      g0 += hv * Whh[(size_t)i * 1536 + tid];
      g1 += hv * Whh[(size_t)i * 1536 + tid + 768];
    }
    ghs[tid] = g0; ghs[tid + 768] = g1;
    __syncthreads();
    if (tid < 512) {
      const float r = sigf(gi[(size_t)step * 1536 + tid] + ghs[tid]);
      const float z = sigf(gi[(size_t)step * 1536 + 512 + tid] + ghs[512 + tid]);
      const float nn = tanhf(gi[(size_t)step * 1536 + 1024 + tid] + r * ghs[1024 + tid]);
      const float hn = (1.f - z) * nn + z * h[tid];
      h[tid] = hn;
      hout[(size_t)step * 512 + tid] = hn;
    }
    __syncthreads();
  }
}

// ------------------------------------------------------------ tiled GEMM
// C[M,N] = A[M,K] @ B[K,N] + bias   (M,N multiples of 64 ONLY)
__launch_bounds__(256)
__global__ void gemm_k(const float* __restrict__ A, const float* __restrict__ B,
                       const float* __restrict__ bias, float* __restrict__ C,
                       int M, int N, int K) {
  __shared__ float As[16][64];
  __shared__ float Bs[16][64];
  const int tid = threadIdx.x;
  const int n0 = blockIdx.x * 64, m0 = blockIdx.y * 64;
  const int tx = tid & 15, ty = tid >> 4;
  const int am = tid >> 2, ak = (tid & 3) << 2;
  const int bk = tid >> 4, bn = (tid & 15) << 2;
  float acc[4][4] = {};
  for (int k0 = 0; k0 < K; k0 += 16) {
    const float4 av = *reinterpret_cast<const float4*>(A + (size_t)(m0 + am) * K + k0 + ak);
    As[ak + 0][am] = av.x; As[ak + 1][am] = av.y; As[ak + 2][am] = av.z; As[ak + 3][am] = av.w;
    const float4 bv = *reinterpret_cast<const float4*>(B + (size_t)(k0 + bk) * N + n0 + bn);
    Bs[bk][bn + 0] = bv.x; Bs[bk][bn + 1] = bv.y; Bs[bk][bn + 2] = bv.z; Bs[bk][bn + 3] = bv.w;
    __syncthreads();
#pragma unroll
    for (int i = 0; i < 16; i++) {
      const float4 a4 = *reinterpret_cast<const float4*>(&As[i][ty * 4]);
      const float4 b4 = *reinterpret_cast<const float4*>(&Bs[i][tx * 4]);
      const float aa[4] = {a4.x, a4.y, a4.z, a4.w};
      const float bb[4] = {b4.x, b4.y, b4.z, b4.w};
#pragma unroll
      for (int x = 0; x < 4; x++)
#pragma unroll
        for (int y = 0; y < 4; y++) acc[x][y] += aa[x] * bb[y];
    }
    __syncthreads();
  }
#pragma unroll
  for (int x = 0; x < 4; x++) {
    const int m = m0 + ty * 4 + x;
#pragma unroll
    for (int y = 0; y < 4; y++) {
      const int n = n0 + tx * 4 + y;
      float v = acc[x][y];
      if (bias) v += bias[n];
      C[(size_t)m * N + n] = v;
    }
  }
}

// ---------------------------- ff2 = relu([seg2[seg_id[t]], ff[t]] @ Wsf + bsf)
// writes TRANSPOSED (D, T) for the TCN.  K=1024.
__launch_bounds__(256)
__global__ void ff2_k(const float* __restrict__ seg2, const float* __restrict__ ff,
                      const int* __restrict__ segid, const float* __restrict__ Wsf,
                      const float* __restrict__ bsf, float* __restrict__ Y, int S) {
  __shared__ float As[16][64];  // [k][m]  m = frame
  __shared__ float Bs[16][64];  // [k][n]  n = out dim
  const int tid = threadIdx.x;
  const int m0 = blockIdx.x * 64;  // frames
  const int n0 = blockIdx.y * 64;  // dims
  const int tx = tid & 15, ty = tid >> 4;
  const int am = tid >> 2, ak = (tid & 3) << 2;
  const int bk = tid >> 4, bn = (tid & 15) << 2;
  const int t = m0 + am;
  int sid = segid[t];
  sid = sid < 0 ? 0 : (sid >= S ? S - 1 : sid);
  float acc[4][4] = {};  // [n][m]
  for (int k0 = 0; k0 < 1024; k0 += 16) {
    const float* src = (k0 + ak < 512) ? (seg2 + (size_t)sid * 512 + k0 + ak)
                                       : (ff + (size_t)t * 512 + (k0 + ak - 512));
    const float4 av = *reinterpret_cast<const float4*>(src);
    As[ak + 0][am] = av.x; As[ak + 1][am] = av.y; As[ak + 2][am] = av.z; As[ak + 3][am] = av.w;
    const float4 bv = *reinterpret_cast<const float4*>(Wsf + (size_t)(k0 + bk) * 512 + n0 + bn);
    Bs[bk][bn + 0] = bv.x; Bs[bk][bn + 1] = bv.y; Bs[bk][bn + 2] = bv.z; Bs[bk][bn + 3] = bv.w;
    __syncthreads();
#pragma unroll
    for (int i = 0; i < 16; i++) {
      const float4 a4 = *reinterpret_cast<const float4*>(&As[i][tx * 4]);
      const float4 b4 = *reinterpret_cast<const float4*>(&Bs[i][ty * 4]);
      const float aa[4] = {a4.x, a4.y, a4.z, a4.w};
      const float bb[4] = {b4.x, b4.y, b4.z, b4.w};
#pragma unroll
      for (int yy = 0; yy < 4; yy++)
#pragma unroll
        for (int xx = 0; xx < 4; xx++) acc[yy][xx] += bb[yy] * aa[xx];
    }
    __syncthreads();
  }
#pragma unroll
  for (int yy = 0; yy < 4; yy++) {
    const int n = n0 + ty * 4 + yy;
    const float bb = bsf[n];
    float4 o;
    o.x = fmaxf(acc[yy][0] + bb, 0.f);
    o.y = fmaxf(acc[yy][1] + bb, 0.f);
    o.z = fmaxf(acc[yy][2] + bb, 0.f);
    o.w = fmaxf(acc[yy][3] + bb, 0.f);
    *reinterpret_cast<float4*>(Y + (size_t)n * TT + m0 + tx * 4) = o;
  }
}

// ------------------------------------------------------------------- TCN conv
// X,Y: (512,T).  NTAPS==1: W[o][i]; NTAPS==3: W[o][i][3]; 'SAME', dilation d<=32.
template<int NTAPS, int RELU, int RES>
__launch_bounds__(256)
__global__ void conv_k(const float* __restrict__ X, const float* __restrict__ W,
                       const float* __restrict__ bias, const float* __restrict__ Res,
                       float* __restrict__ Y, int dil) {
  __shared__ float Xs[16][128];
  __shared__ float Ws[NTAPS][16][64];
  const int t0 = blockIdx.x * 64, c0 = blockIdx.y * 64;
  const int d = (NTAPS == 3) ? dil : 0;
  const int width = 64 + 2 * d;
  const int tid = threadIdx.x, tx = tid & 15, ty = tid >> 4;
  const int wc = tid >> 2, wi0 = (tid & 3) << 2;
  float acc[4][4] = {};  // [c][t]
  for (int k0 = 0; k0 < 512; k0 += 16) {
    for (int e = tid; e < 16 * width; e += 256) {
      const int ttl = e % width, ii = e / width;
      const int gt = t0 - d + ttl;
      Xs[ii][ttl] = (gt >= 0 && gt < TT) ? X[(size_t)(k0 + ii) * TT + gt] : 0.f;
    }
    if (NTAPS == 1) {
      const float4 wv = *reinterpret_cast<const float4*>(W + (size_t)(c0 + wc) * 512 + k0 + wi0);
      Ws[0][wi0 + 0][wc] = wv.x; Ws[0][wi0 + 1][wc] = wv.y;
      Ws[0][wi0 + 2][wc] = wv.z; Ws[0][wi0 + 3][wc] = wv.w;
    } else {
#pragma unroll
      for (int j = 0; j < 4; j++)
#pragma unroll
        for (int tap = 0; tap < NTAPS; tap++)
          Ws[tap][wi0 + j][wc] = W[((size_t)(c0 + wc) * 512 + k0 + wi0 + j) * 3 + tap];
    }
    __syncthreads();
#pragma unroll
    for (int i = 0; i < 16; i++) {
#pragma unroll
      for (int tap = 0; tap < NTAPS; tap++) {
        const float4 w4 = *reinterpret_cast<const float4*>(&Ws[tap][i][ty * 4]);
        const float wv4[4] = {w4.x, w4.y, w4.z, w4.w};
        const int xb = tx * 4 + tap * d;
        float xv[4];
        xv[0] = Xs[i][xb + 0]; xv[1] = Xs[i][xb + 1];
        xv[2] = Xs[i][xb + 2]; xv[3] = Xs[i][xb + 3];
#pragma unroll
        for (int a = 0; a < 4; a++)
#pragma unroll
          for (int b = 0; b < 4; b++) acc[a][b] += wv4[a] * xv[b];
      }
    }
    __syncthreads();
  }
#pragma unroll
  for (int a = 0; a < 4; a++) {
    const int c = c0 + ty * 4 + a;
    const float bb = bias[c];
    float vals[4];
#pragma unroll
    for (int b = 0; b < 4; b++) {
      float v = acc[a][b] + bb;
      if (RES) v += Res[(size_t)c * TT + t0 + tx * 4 + b];
      if (RELU) v = fmaxf(v, 0.f);
      vals[b] = v;
    }
    *reinterpret_cast<float4*>(Y + (size_t)c * TT + t0 + tx * 4) =
        make_float4(vals[0], vals[1], vals[2], vals[3]);
  }
}

// -------------------- tiled transpose (512,T) -> out (T,512) + f32 copy (T,512)
__launch_bounds__(256)
__global__ void temit_k(const float* __restrict__ Xin, float* __restrict__ outp,
                        float* __restrict__ Aout) {
  __shared__ float tile[32][33];
  const int t0 = blockIdx.x * 32, d0 = blockIdx.y * 32;
  const int lx = threadIdx.x & 31, ly = threadIdx.x >> 5;
#pragma unroll
  for (int r = 0; r < 4; r++)
    tile[ly + 8 * r][lx] = Xin[(size_t)(d0 + ly + 8 * r) * TT + t0 + lx];
  __syncthreads();
#pragma unroll
  for (int r = 0; r < 4; r++) {
    const int t = t0 + ly + 8 * r, dd = d0 + lx;
    const float v = tile[lx][ly + 8 * r];
    outp[(size_t)t * 512 + dd] = v;
    Aout[(size_t)t * 512 + dd] = v;
  }
}

// ---------------------------------------------------------------- cosine sim
__global__ void nsim_k(const float* __restrict__ V, const float* __restrict__ text,
                       const float* __restrict__ tnorm, float* __restrict__ out, int R) {
  int idx = blockIdx.x * 256 + threadIdx.x;  // r*32 + c
  if (idx >= R * 32) return;
  int r = idx >> 5, c = idx & 31;
  const float* vr = V + (size_t)r * 512;
  float ss = 0.f, dot = 0.f;
  for (int dd = 0; dd < 512; dd++) {
    float v = vr[dd];
    ss += v * v;
    dot += v * text[(size_t)c * 512 + dd];
  }
  out[idx] = dot / (sqrtf(ss) * tnorm[c]);
}

// ======================================================================= host
extern "C" void kernel_launch(void* const* d_in, const int* in_sizes, int n_in,
                              void* d_out, int out_size, void* d_ws, size_t ws_size,
                              hipStream_t stream) {
  const float* in_ff   = (const float*)d_in[0];
  const float* in_act  = (const float*)d_in[1];
  const float* in_fpos = (const float*)d_in[2];
  const float* in_apos = (const float*)d_in[3];
  const float* in_text = (const float*)d_in[4];
  const float* Wf2c = (const float*)d_in[5];  const float* bf2c = (const float*)d_in[6];
  const float* Wa2c = (const float*)d_in[7];  const float* ba2c = (const float*)d_in[8];
  const float* Ws2c = (const float*)d_in[9];  const float* bs2c = (const float*)d_in[10];
  const float* Wih_f = (const float*)d_in[11]; const float* Whh_f = (const float*)d_in[12];
  const float* bih_f = (const float*)d_in[13]; const float* bhh_f = (const float*)d_in[14];
  const float* Wih_b = (const float*)d_in[15]; const float* Whh_b = (const float*)d_in[16];
  const float* bih_b = (const float*)d_in[17]; const float* bhh_b = (const float*)d_in[18];
  const float* Wcomb = (const float*)d_in[19]; const float* bcomb = (const float*)d_in[20];
  const float* f2a_Wq = (const float*)d_in[21]; const float* f2a_Wk = (const float*)d_in[22];
  const float* f2a_Wv = (const float*)d_in[23]; const float* f2a_Wo = (const float*)d_in[24];
  const float* f2a_bo = (const float*)d_in[25];
  const float* ag_Wih = (const float*)d_in[26]; const float* ag_Whh = (const float*)d_in[27];
  const float* ag_bih = (const float*)d_in[28]; const float* ag_bhh = (const float*)d_in[29];
  const float* a2f_Wq = (const float*)d_in[30]; const float* a2f_Wk = (const float*)d_in[31];
  const float* a2f_Wv = (const float*)d_in[32]; const float* a2f_Wo = (const float*)d_in[33];
  const float* a2f_bo = (const float*)d_in[34];
  const float* Wsf = (const float*)d_in[35]; const float* bsf = (const float*)d_in[36];
  const float* tcn_inW = (const float*)d_in[37]; const float* tcn_inb = (const float*)d_in[38];
  const float* tcn_dW = (const float*)d_in[39]; const float* tcn_db = (const float*)d_in[40];
  const float* tcn_pW = (const float*)d_in[41]; const float* tcn_pb = (const float*)d_in[42];
  const float* tcn_outW = (const float*)d_in[43]; const float* tcn_outb = (const float*)d_in[44];

  int S = (out_size - (TT * DD + MM * DD + TT * CC + MM * CC)) / CC;
  if (S < 1) S = 1;
  if (S > TT) S = TT;

  // ---------------- workspace layout
  char* ws = (char*)d_ws;
  size_t off = 0;
  auto alloc = [&](size_t b) -> char* { char* p = ws + off; off += (b + 255) & ~(size_t)255; return p; };
  const size_t BTD = (size_t)TT * DD * 4;
  float* bufA = (float*)alloc(BTD);
  float* bufB = (float*)alloc(BTD);
  int* pred    = (int*)alloc((size_t)TT * 4);
  int* segid   = (int*)alloc((size_t)TT * 4);
  int* starts  = (int*)alloc((size_t)TT * 4);
  int* centers = (int*)alloc((size_t)TT * 4);
  int* cnts    = (int*)alloc((size_t)TT * 4);
  float* tnorm = (float*)alloc(32 * 4);
  float* segmean = (float*)alloc((size_t)S * 512 * 4);
  float* gif  = (float*)alloc((size_t)S * 768 * 4);
  float* gib  = (float*)alloc((size_t)S * 768 * 4);
  float* hfb  = (float*)alloc((size_t)S * 256 * 4);
  float* hbb  = (float*)alloc((size_t)S * 256 * 4);
  float* acmb = (float*)alloc((size_t)S * 512 * 4);
  float* segc = (float*)alloc((size_t)S * 512 * 4);
  float* segpos = (float*)alloc((size_t)S * 512 * 4);
  float* kin  = (float*)alloc((size_t)S * 512 * 4);
  float* kf2a = (float*)alloc((size_t)S * 512 * 4);
  float* vf2a = (float*)alloc((size_t)S * 512 * 4);
  float* q2   = (float*)alloc((size_t)S * 512 * 4);
  float* att2 = (float*)alloc((size_t)S * 512 * 4);
  float* seg2 = (float*)alloc((size_t)S * 512 * 4);
  float* vseg = (float*)alloc((size_t)S * 512 * 4);
  float* pbuf = (float*)alloc((size_t)64 * S * 4);
  float* qin  = (float*)alloc((size_t)64 * 512 * 4);
  float* qf2a = (float*)alloc((size_t)64 * 512 * 4);
  float* att1 = (float*)alloc((size_t)64 * 512 * 4);
  float* af0  = (float*)alloc((size_t)64 * 512 * 4);
  float* aggi = (float*)alloc((size_t)64 * 1536 * 4);
  float* afg  = (float*)alloc((size_t)64 * 512 * 4);
  float* k2in = (float*)alloc((size_t)64 * 512 * 4);
  float* k2   = (float*)alloc((size_t)64 * 512 * 4);
  float* v2   = (float*)alloc((size_t)64 * 512 * 4);
  float* vaf  = (float*)alloc((size_t)64 * 512 * 4);
  (void)ws_size; (void)in_sizes; (void)n_in;

  float* outp = (float*)d_out;
  float* out_ff   = outp;
  float* out_af   = outp + (size_t)TT * DD;
  float* out_fsim = out_af + (size_t)MM * DD;
  float* out_asim = out_fsim + (size_t)TT * CC;
  float* out_ssim = out_asim + (size_t)MM * CC;

  auto GR = [](long n) { return (unsigned)((n + 255) / 256); };

  // zero small ws region (defensive; GRU h0 lives in LDS now)
  zero_k<<<2048, 256, 0, stream>>>((float*)d_ws, (long)(off / 4));

  tnorm_k<<<1, 256, 0, stream>>>(in_text, tnorm);

  // segmentation (tiled GEMM for the T-sized projection)
  gemm_k<<<dim3(8, 128), 256, 0, stream>>>(in_ff, Wf2c, bf2c, bufA, TT, 512, 512);
  nargmax_k<<<GR(TT), 256, 0, stream>>>(bufA, in_text, tnorm, pred);
  nseg_k<<<1, 64, 0, stream>>>(pred, segid, starts, centers, cnts);
  segmean_k<<<GR((long)S * 512), 256, 0, stream>>>(in_ff, starts, cnts, segmean, S);

  // seg BiGRU (fused scan kernels)
  ngemm_k<<<GR((long)S * 768), 256, 0, stream>>>(segmean, Wih_f, bih_f, gif, S, 768, 512);
  ngemm_k<<<GR((long)S * 768), 256, 0, stream>>>(segmean, Wih_b, bih_b, gib, S, 768, 512);
  gru_seg_k<<<2, 768, 0, stream>>>(gif, gib, Whh_f, bhh_f, Whh_b, bhh_b, hfb, hbb, S);
  acomb_k<<<GR((long)S * 512), 256, 0, stream>>>(hfb, hbb, acmb, S * 512);
  ngemm_k<<<GR((long)S * 512), 256, 0, stream>>>(acmb, Wcomb, bcomb, segc, S, 512, 512);
  gatherpos_k<<<GR((long)S * 512), 256, 0, stream>>>(in_fpos, centers, segpos, S * 512);

  // f2a attention (actions query segments)
  addff_k<<<GR(64 * 512), 256, 0, stream>>>(in_act, in_apos, qin, 64 * 512);
  addff_k<<<GR((long)S * 512), 256, 0, stream>>>(segc, segpos, kin, S * 512);
  ngemm_k<<<GR(64 * 512), 256, 0, stream>>>(qin, f2a_Wq, nullptr, qf2a, 64, 512, 512);
  ngemm_k<<<GR((long)S * 512), 256, 0, stream>>>(kin, f2a_Wk, nullptr, kf2a, S, 512, 512);
  ngemm_k<<<GR((long)S * 512), 256, 0, stream>>>(segc, f2a_Wv, nullptr, vf2a, S, 512, 512);
  nlogit_k<<<GR((long)64 * S), 256, 0, stream>>>(qf2a, kf2a, pbuf, 64, S);
  nsoft_k<<<1, 256, 0, stream>>>(pbuf, 64, S);
  nav_k<<<GR(64 * 512), 256, 0, stream>>>(pbuf, vf2a, att1, 64, S);
  ngemm_k<<<GR(64 * 512), 256, 0, stream>>>(att1, f2a_Wo, f2a_bo, af0, 64, 512, 512);

  // action GRU (fused scan)
  ngemm_k<<<GR(64 * 1536), 256, 0, stream>>>(af0, ag_Wih, ag_bih, aggi, 64, 1536, 512);
  gru_act_k<<<1, 768, 0, stream>>>(aggi, ag_Whh, ag_bhh, afg, MM);
  copy_k<<<GR(64 * 512), 256, 0, stream>>>(afg, out_af, 64 * 512);

  // a2f attention (segments query actions)
  addff_k<<<GR(64 * 512), 256, 0, stream>>>(afg, in_apos, k2in, 64 * 512);
  ngemm_k<<<GR((long)S * 512), 256, 0, stream>>>(kin, a2f_Wq, nullptr, q2, S, 512, 512);
  ngemm_k<<<GR(64 * 512), 256, 0, stream>>>(k2in, a2f_Wk, nullptr, k2, 64, 512, 512);
  ngemm_k<<<GR(64 * 512), 256, 0, stream>>>(afg, a2f_Wv, nullptr, v2, 64, 512, 512);
  nlogit_k<<<GR((long)S * 64), 256, 0, stream>>>(q2, k2, pbuf, S, 64);
  nsoft_k<<<GR(S), 256, 0, stream>>>(pbuf, S, 64);
  nav_k<<<GR((long)S * 512), 256, 0, stream>>>(pbuf, v2, att2, S, 64);
  ngemm_k<<<GR((long)S * 512), 256, 0, stream>>>(att2, a2f_Wo, a2f_bo, seg2, S, 512, 512);

  // frame fusion + TCN (tiled), ping-pong bufA <-> bufB as (D,T)
  ff2_k<<<dim3(128, 8), 256, 0, stream>>>(seg2, in_ff, segid, Wsf, bsf, bufA, S);
  conv_k<1, 0, 0><<<dim3(128, 8), 256, 0, stream>>>(bufA, tcn_inW, tcn_inb, nullptr, bufB, 1);
  for (int l = 0; l < 6; l++) {
    conv_k<3, 1, 0><<<dim3(128, 8), 256, 0, stream>>>(
        bufB, tcn_dW + (size_t)l * 512 * 512 * 3, tcn_db + (size_t)l * 512, nullptr, bufA, 1 << l);
    conv_k<1, 0, 1><<<dim3(128, 8), 256, 0, stream>>>(
        bufA, tcn_pW + (size_t)l * 512 * 512, tcn_pb + (size_t)l * 512, bufB, bufB, 1);
  }
  conv_k<1, 0, 0><<<dim3(128, 8), 256, 0, stream>>>(bufB, tcn_outW, tcn_outb, nullptr, bufA, 1);
  temit_k<<<dim3(256, 16), 256, 0, stream>>>(bufA, out_ff, bufB);

  // similarity heads (tiled GEMM for the T-sized projection)
  gemm_k<<<dim3(8, 128), 256, 0, stream>>>(bufB, Wf2c, bf2c, bufA, TT, 512, 512);
  nsim_k<<<GR((long)TT * 32), 256, 0, stream>>>(bufA, in_text, tnorm, out_fsim, TT);
  ngemm_k<<<GR(64 * 512), 256, 0, stream>>>(afg, Wa2c, ba2c, vaf, 64, 512, 512);
  nsim_k<<<GR(64 * 32), 256, 0, stream>>>(vaf, in_text, tnorm, out_asim, 64);
  ngemm_k<<<GR((long)S * 512), 256, 0, stream>>>(seg2, Ws2c, bs2c, vseg, S, 512, 512);
  nsim_k<<<GR((long)S * 32), 256, 0, stream>>>(vseg, in_text, tnorm, out_ssim, S);
}